// Round 1
// baseline (363.121 us; speedup 1.0000x reference)
//
#include <hip/hip_runtime.h>
#include <math.h>

#define DIMF 1024

// One wave (64 lanes) per row of `features`. Lane l covers columns
// {k*256 + l*4 .. +3} for k=0..3 (float4, each instruction spans the wave's
// contiguous 1 KB — perfectly coalesced). W_proj fragments live in registers
// and are reused across grid-stride rows.
__global__ __launch_bounds__(256) void qkc_kernel(
    const float* __restrict__ features,
    const float* __restrict__ W_proj,
    const float* __restrict__ b_proj,
    const float* __restrict__ ref_vec,
    const float* __restrict__ W_cls,
    const float* __restrict__ b_cls,
    float* __restrict__ out,
    int nrows)
{
    const int lane = threadIdx.x & 63;
    const int wib  = threadIdx.x >> 6;
    const int wpb  = blockDim.x >> 6;
    const int gwave  = blockIdx.x * wpb + wib;
    const int nwaves = gridDim.x * wpb;

    // W_proj fragments: w[q][k] = W_proj[q][k*256 + lane*4 .. +3]
    float4 w[4][4];
    #pragma unroll
    for (int q = 0; q < 4; ++q)
        #pragma unroll
        for (int k = 0; k < 4; ++k)
            w[q][k] = *reinterpret_cast<const float4*>(
                &W_proj[q * DIMF + k * 256 + lane * 4]);

    // Scalar params (tiny, cached in L2/L3; every wave computes them once)
    float u[4], bp[4];
    #pragma unroll
    for (int q = 0; q < 4; ++q) {
        u[q]  = tanhf(ref_vec[q]);
        bp[q] = b_proj[q];
    }
    const float wc = W_cls[0];
    const float bc = b_cls[0];

    for (int row = gwave; row < nrows; row += nwaves) {
        const float* frow = features + (size_t)row * DIMF;
        float4 f[4];
        #pragma unroll
        for (int k = 0; k < 4; ++k)
            f[k] = *reinterpret_cast<const float4*>(&frow[k * 256 + lane * 4]);

        float acc[4];
        #pragma unroll
        for (int q = 0; q < 4; ++q) {
            float s = f[0].x * w[q][0].x + f[0].y * w[q][0].y
                    + f[0].z * w[q][0].z + f[0].w * w[q][0].w;
            #pragma unroll
            for (int k = 1; k < 4; ++k)
                s += f[k].x * w[q][k].x + f[k].y * w[q][k].y
                   + f[k].z * w[q][k].z + f[k].w * w[q][k].w;
            // full-wave butterfly reduce (64 lanes)
            #pragma unroll
            for (int off = 32; off >= 1; off >>= 1)
                s += __shfl_xor(s, off, 64);
            acc[q] = s;
        }

        if (lane == 0) {
            float fid = 1.0f;
            #pragma unroll
            for (int q = 0; q < 4; ++q) {
                float t = tanhf(acc[q] + bp[q]);
                float c = cosf((t - u[q]) * 0.5f);
                fid *= c * c;
            }
            out[row] = fid * wc + bc;
        }
    }
}

extern "C" void kernel_launch(void* const* d_in, const int* in_sizes, int n_in,
                              void* d_out, int out_size, void* d_ws, size_t ws_size,
                              hipStream_t stream) {
    const float* features = (const float*)d_in[0];
    const float* W_proj   = (const float*)d_in[1];
    const float* b_proj   = (const float*)d_in[2];
    const float* ref_vec  = (const float*)d_in[3];
    const float* W_cls    = (const float*)d_in[4];
    const float* b_cls    = (const float*)d_in[5];
    float* out = (float*)d_out;

    const int nrows = out_size;          // 65536 rows, 1 output each
    const int block = 256;               // 4 waves/block
    const int wpb = block / 64;
    int blocks = (nrows + wpb - 1) / wpb;
    if (blocks > 2048) blocks = 2048;    // grid-stride the rest

    qkc_kernel<<<blocks, block, 0, stream>>>(
        features, W_proj, b_proj, ref_vec, W_cls, b_cls, out, nrows);
}

// Round 2
// 362.777 us; speedup vs baseline: 1.0009x; 1.0009x over previous
//
#include <hip/hip_runtime.h>
#include <math.h>

#define DIMF 1024
#define RPW  8   // rows processed per wave (batched epilogue width)

// tanh(x) = 1 - 2/(exp(2x)+1)  (monotone, exact at +-inf; err ~1e-7 rel)
__device__ __forceinline__ float fast_tanh(float x) {
    float e = __expf(2.0f * x);
    return 1.0f - __fdividef(2.0f, e + 1.0f);
}

// One wave per row-slice: lane l covers columns {k*256 + l*4 ..+3}, k=0..3.
// Each wave handles RPW rows (row = gwave + i*nwaves). After the butterfly
// reduce, every lane holds the full sums; lane i keeps row i's 4 sums, so the
// tanh/cos epilogue runs ONCE per wave with 8 rows in parallel across lanes.
__global__ __launch_bounds__(256, 4) void qkc_kernel(
    const float* __restrict__ features,
    const float* __restrict__ W_proj,
    const float* __restrict__ b_proj,
    const float* __restrict__ ref_vec,
    const float* __restrict__ W_cls,
    const float* __restrict__ b_cls,
    float* __restrict__ out,
    int nrows, int nwaves)
{
    const int lane  = threadIdx.x & 63;
    const int wib   = threadIdx.x >> 6;
    const int gwave = blockIdx.x * (blockDim.x >> 6) + wib;

    // W_proj fragments in registers (64 VGPRs), reused across all rows.
    float4 w[4][4];
    #pragma unroll
    for (int q = 0; q < 4; ++q)
        #pragma unroll
        for (int k = 0; k < 4; ++k)
            w[q][k] = *reinterpret_cast<const float4*>(
                &W_proj[q * DIMF + k * 256 + lane * 4]);

    float u[4], bp[4];
    #pragma unroll
    for (int q = 0; q < 4; ++q) {
        u[q]  = fast_tanh(ref_vec[q]);
        bp[q] = b_proj[q];
    }
    const float wc = W_cls[0];
    const float bc = b_cls[0];

    float e[4] = {0.f, 0.f, 0.f, 0.f};   // lane i <- row i's 4 dot sums

    #pragma unroll
    for (int i = 0; i < RPW; ++i) {
        const int row = gwave + i * nwaves;       // wave-uniform guard
        if (row < nrows) {
            const float* frow = features + (size_t)row * DIMF;
            float4 f0 = *reinterpret_cast<const float4*>(&frow[        lane * 4]);
            float4 f1 = *reinterpret_cast<const float4*>(&frow[256  +  lane * 4]);
            float4 f2 = *reinterpret_cast<const float4*>(&frow[512  +  lane * 4]);
            float4 f3 = *reinterpret_cast<const float4*>(&frow[768  +  lane * 4]);

            #pragma unroll
            for (int q = 0; q < 4; ++q) {
                float s = f0.x * w[q][0].x + f0.y * w[q][0].y
                        + f0.z * w[q][0].z + f0.w * w[q][0].w
                        + f1.x * w[q][1].x + f1.y * w[q][1].y
                        + f1.z * w[q][1].z + f1.w * w[q][1].w
                        + f2.x * w[q][2].x + f2.y * w[q][2].y
                        + f2.z * w[q][2].z + f2.w * w[q][2].w
                        + f3.x * w[q][3].x + f3.y * w[q][3].y
                        + f3.z * w[q][3].z + f3.w * w[q][3].w;
                #pragma unroll
                for (int off = 32; off >= 1; off >>= 1)
                    s += __shfl_xor(s, off, 64);
                if (lane == i) e[q] = s;          // 1 cndmask, no divergence cost
            }
        }
    }

    // Batched epilogue: lanes 0..RPW-1 each finish one row.
    // fidelity = prod_q cos^2((t_q-u_q)/2) = prod_q (1+cos(t_q-u_q))/2
    float fid = 1.0f;
    #pragma unroll
    for (int q = 0; q < 4; ++q) {
        float t = fast_tanh(e[q] + bp[q]);
        float c = __cosf(t - u[q]);
        fid *= 0.5f * (1.0f + c);
    }
    const int orow = gwave + lane * nwaves;
    if (lane < RPW && orow < nrows)
        out[orow] = fid * wc + bc;
}

extern "C" void kernel_launch(void* const* d_in, const int* in_sizes, int n_in,
                              void* d_out, int out_size, void* d_ws, size_t ws_size,
                              hipStream_t stream) {
    const float* features = (const float*)d_in[0];
    const float* W_proj   = (const float*)d_in[1];
    const float* b_proj   = (const float*)d_in[2];
    const float* ref_vec  = (const float*)d_in[3];
    const float* W_cls    = (const float*)d_in[4];
    const float* b_cls    = (const float*)d_in[5];
    float* out = (float*)d_out;

    const int nrows = out_size;                  // 65536
    const int block = 256;                       // 4 waves/block
    const int wpb   = block / 64;
    const int target_waves = (nrows + RPW - 1) / RPW;
    int blocks = (target_waves + wpb - 1) / wpb; // 2048 for 65536 rows
    const int nwaves = blocks * wpb;

    qkc_kernel<<<blocks, block, 0, stream>>>(
        features, W_proj, b_proj, ref_vec, W_cls, b_cls, out, nrows, nwaves);
}